// Round 6
// baseline (377.856 us; speedup 1.0000x reference)
//
#include <hip/hip_runtime.h>
#include <hip/hip_bf16.h>
#include <math.h>

#define BB 8
#define SS 1024
#define DD 768
#define HH 12
#define HDD 64
#define FFF 3072
#define NROW (BB*SS)
#define QKVN (3*DD)

typedef __hip_bfloat16 bf16;
typedef __bf16 bf16x8 __attribute__((ext_vector_type(8)));
typedef float floatx4 __attribute__((ext_vector_type(4)));

// tanh-form GELU: ~9 VALU ops (exp+rcp) vs ~30 for erff; max abs err ~1e-3.
__device__ __forceinline__ float gelu_fast(float x) {
    float u = x * fmaf(0.07135481627f, x * x, 1.595769122f);
    float e = __expf(u);
    return x * e * __builtin_amdgcn_rcpf(e + 1.0f);
}

__device__ __forceinline__ unsigned short f2bfbits(float f) {
    bf16 h = __float2bfloat16(f);
    return __builtin_bit_cast(unsigned short, h);
}

__device__ __forceinline__ void gload16(const void* g, void* l) {
    __builtin_amdgcn_global_load_lds(
        (const __attribute__((address_space(1))) unsigned int*)g,
        (__attribute__((address_space(3))) unsigned int*)l, 16, 0, 0);
}

// ---------------- LayerNorm: one WAVE per row, vectorized, zero barriers -----------
template<typename T>
__global__ __launch_bounds__(256) void ln_kernel(const T* __restrict__ x,
                                                 const float* __restrict__ w,
                                                 const float* __restrict__ b,
                                                 bf16* __restrict__ y) {
    int wave = threadIdx.x >> 6, lane = threadIdx.x & 63;
    int row = blockIdx.x * 4 + wave;
    const T* xr = x + (size_t)row * DD;
    bf16* yr = y + (size_t)row * DD;

    float v[12];
    #pragma unroll
    for (int s = 0; s < 3; s++) {
        int base = s * 256 + lane * 4;
        if constexpr (__is_same(T, float)) {
            float4 f = *(const float4*)(xr + base);
            v[s*4+0] = f.x; v[s*4+1] = f.y; v[s*4+2] = f.z; v[s*4+3] = f.w;
        } else {
            ushort4 u = *(const ushort4*)(xr + base);
            v[s*4+0] = __bfloat162float(__builtin_bit_cast(bf16, u.x));
            v[s*4+1] = __bfloat162float(__builtin_bit_cast(bf16, u.y));
            v[s*4+2] = __bfloat162float(__builtin_bit_cast(bf16, u.z));
            v[s*4+3] = __bfloat162float(__builtin_bit_cast(bf16, u.w));
        }
    }
    float sum = 0.f, sq = 0.f;
    #pragma unroll
    for (int i = 0; i < 12; i++) { sum += v[i]; sq += v[i] * v[i]; }
    #pragma unroll
    for (int off = 1; off < 64; off <<= 1) {
        sum += __shfl_xor(sum, off, 64);
        sq  += __shfl_xor(sq,  off, 64);
    }
    float mu  = sum * (1.0f / DD);
    float var = sq * (1.0f / DD) - mu * mu;
    float inv = rsqrtf(var + 1e-5f);

    #pragma unroll
    for (int s = 0; s < 3; s++) {
        int base = s * 256 + lane * 4;
        float4 wf = *(const float4*)(w + base);
        float4 bf = *(const float4*)(b + base);
        ushort4 o;
        o.x = f2bfbits((v[s*4+0] - mu) * inv * wf.x + bf.x);
        o.y = f2bfbits((v[s*4+1] - mu) * inv * wf.y + bf.y);
        o.z = f2bfbits((v[s*4+2] - mu) * inv * wf.z + bf.z);
        o.w = f2bfbits((v[s*4+3] - mu) * inv * wf.w + bf.w);
        *(ushort4*)(yr + base) = o;
    }
}

// ------------- fused weight prep: all transposes+casts + bias concat, ONE launch ---
__global__ __launch_bounds__(256) void prep_kernel(
    const float* __restrict__ Wq, const float* __restrict__ Wk,
    const float* __restrict__ Wv, const float* __restrict__ Wp,
    const float* __restrict__ W1, const float* __restrict__ W2,
    const float* __restrict__ bq, const float* __restrict__ bk,
    const float* __restrict__ bv,
    bf16* __restrict__ Wqkvt, bf16* __restrict__ Wpt,
    bf16* __restrict__ W1t, bf16* __restrict__ W2t, float* __restrict__ bqkv)
{
    int id = blockIdx.x;
    if (id >= 6912) {
        int i = (id - 6912) * 256 + threadIdx.x;
        if (i < DD) { bqkv[i] = bq[i]; bqkv[DD + i] = bk[i]; bqkv[2*DD + i] = bv[i]; }
        return;
    }
    const float* src; bf16* dst; int K, N, hmode, local;
    if (id < 1728)      { K = DD;  N = DD;  hmode = 1; local = id % 576;
                          src = (id < 576) ? Wq : (id < 1152 ? Wk : Wv);
                          dst = Wqkvt + (size_t)(id / 576) * DD * DD; }
    else if (id < 2304) { K = DD;  N = DD;  hmode = 0; local = id - 1728; src = Wp; dst = Wpt; }
    else if (id < 4608) { K = DD;  N = FFF; hmode = 0; local = id - 2304; src = W1; dst = W1t; }
    else                { K = FFF; N = DD;  hmode = 0; local = id - 4608; src = W2; dst = W2t; }
    int ktiles = K / 32;
    int k0 = (local % ktiles) * 32, n0 = (local / ktiles) * 32;
    __shared__ float t[32][33];
    int tx = threadIdx.x & 31, ty4 = threadIdx.x >> 5;
    #pragma unroll
    for (int i = 0; i < 4; i++) {
        int k = k0 + ty4 * 4 + i;
        int n = n0 + tx;
        size_t si = hmode ? ((size_t)(n >> 6) * K * 64 + (size_t)k * 64 + (n & 63))
                          : ((size_t)k * N + n);
        t[ty4 * 4 + i][tx] = src[si];
    }
    __syncthreads();
    #pragma unroll
    for (int i = 0; i < 4; i++) {
        int n = n0 + ty4 * 4 + i;
        int k = k0 + tx;
        dst[(size_t)n * K + k] = __float2bfloat16(t[tx][ty4 * 4 + i]);
    }
}

// ---------------- MFMA bf16 GEMM: C = epi(A @ Bt^T) --------------------------------
// 1D grid, XCD-cooperative: xcd = id&7 owns `py` full row-panels x all `nx` col
// tiles. LDS chunk-XOR-swizzled: conflict-free frag reads (BANK_CONFLICT = 0).
// MEASURED (r2-r5): dur invariant to MT(64/128), KH(1/2), DEPTH(2/3) at 48KB LDS —
// all give 3 blocks/CU, occupancy 28%, MfmaUtil 21%. The kernel is latency-bound
// with LDS as the occupancy cap (VGPR=68 would allow 7 waves/SIMD).
// => FF1 uses KH=1 (24KB LDS): 6 blocks/CU, 24 waves/CU, stalls overlap across
//    blocks (m114 mechanism). DEPTH=3 counted-vmcnt measured neutral; kept for QKV.
template<int MT, int KH, int DEPTH>
__global__ __launch_bounds__(256) void mfma_gemm(
    const bf16* __restrict__ A, const bf16* __restrict__ Bt,
    const float* __restrict__ bias, const float* __restrict__ residf,
    const bf16* __restrict__ residb, void* __restrict__ Cout,
    int M, int N, int K, int act, int out_bf16, int nx, int py,
    int qkvmode, bf16* __restrict__ qhg, bf16* __restrict__ khg, bf16* __restrict__ vtg)
{
    constexpr int MFRAG = MT / 32;
    constexpr int ACH = MT * 4;
    constexpr int LOADS = ACH * KH / 256 + 2 * KH;   // gload16 per thread per stage
    static_assert(DEPTH == 2 || (DEPTH == 3 && LOADS == 4), "vmcnt literal fixed at 4");
    __shared__ bf16 As[DEPTH][KH * MT * 32];
    __shared__ bf16 Bs[DEPTH][KH * 128 * 32];
    int tid = threadIdx.x;
    int id = blockIdx.x;
    int xcd = id & 7, slot = id >> 3;
    int row0 = (xcd * py + slot / nx) * MT, col0 = (slot % nx) * 128;
    int wave = tid >> 6, lane = tid & 63;
    int wm = (wave >> 1) * (MT / 2), wn = (wave & 1) * 64;
    int l16 = lane & 15, quad = lane >> 4;

    auto stage = [&](int k0, int buf) {
        #pragma unroll
        for (int i = 0; i < ACH * KH / 256; i++) {
            int c = tid + i * 256;
            int half = c / ACH, rem = c % ACH;
            int r = rem >> 2, pos = rem & 3;
            int ksw = k0 + half * 32 + ((pos ^ ((r >> 1) & 3)) << 3);
            gload16(A + (size_t)(row0 + r) * K + ksw, &As[buf][c * 8]);
        }
        #pragma unroll
        for (int i = 0; i < 2 * KH; i++) {
            int c = tid + i * 256;
            int half = c >> 9, rem = c & 511;
            int r = rem >> 2, pos = rem & 3;
            int ksw = k0 + half * 32 + ((pos ^ ((r >> 1) & 3)) << 3);
            gload16(Bt + (size_t)(col0 + r) * K + ksw, &Bs[buf][c * 8]);
        }
    };

    floatx4 acc[MFRAG][4] = {};

    auto compute = [&](int cur) {
        #pragma unroll
        for (int s = 0; s < KH; s++) {
            bf16x8 af[MFRAG], bfr[4];
            #pragma unroll
            for (int mt = 0; mt < MFRAG; mt++) {
                int r = wm + mt * 16 + l16;
                int pos = quad ^ ((r >> 1) & 3);
                af[mt] = *(const bf16x8*)&As[cur][s * MT * 32 + r * 32 + pos * 8];
            }
            #pragma unroll
            for (int nt = 0; nt < 4; nt++) {
                int r = wn + nt * 16 + l16;
                int pos = quad ^ ((r >> 1) & 3);
                bfr[nt] = *(const bf16x8*)&Bs[cur][s * 4096 + r * 32 + pos * 8];
            }
            #pragma unroll
            for (int mt = 0; mt < MFRAG; mt++)
                #pragma unroll
                for (int nt = 0; nt < 4; nt++)
                    acc[mt][nt] = __builtin_amdgcn_mfma_f32_16x16x32_bf16(
                        af[mt], bfr[nt], acc[mt][nt], 0, 0, 0);
        }
    };

    if constexpr (DEPTH == 3) {
        int T = K / (32 * KH);
        stage(0, 0);
        if (T > 1) stage(32 * KH, 1);
        for (int t = 0; t < T; t++) {
            if (t == T - 1) { asm volatile("s_waitcnt vmcnt(0)" ::: "memory"); }
            else            { asm volatile("s_waitcnt vmcnt(4)" ::: "memory"); }
            __builtin_amdgcn_s_barrier();
            if (t + 2 < T) stage((t + 2) * (32 * KH), (t + 2) % 3);
            compute(t % 3);
        }
    } else {
        stage(0, 0);
        int cur = 0;
        for (int k0 = 0; k0 < K; k0 += 32 * KH) {
            __syncthreads();
            if (k0 + 32 * KH < K) stage(k0 + 32 * KH, cur ^ 1);
            compute(cur);
            cur ^= 1;
        }
    }

    if (qkvmode) {
        #pragma unroll
        for (int mt = 0; mt < MFRAG; mt++) {
            int rbase = row0 + wm + mt * 16 + quad * 4;
            int bq_ = rbase >> 10, sb = rbase & 1023;
            #pragma unroll
            for (int nt = 0; nt < 4; nt++) {
                int col = col0 + wn + nt * 16 + l16;
                float bcol = bias[col];
                if (col < DD) {
                    int hh = col >> 6, e = col & 63;
                    bf16* base = qhg + (((size_t)bq_ * HH + hh) * SS + sb) * 64 + e;
                    #pragma unroll
                    for (int r = 0; r < 4; r++)
                        base[(size_t)r * 64] = __float2bfloat16(acc[mt][nt][r] + bcol);
                } else if (col < 2 * DD) {
                    int cc = col - DD, hh = cc >> 6, e = cc & 63;
                    bf16* base = khg + (((size_t)bq_ * HH + hh) * SS) * 64;
                    #pragma unroll
                    for (int r = 0; r < 4; r++) {
                        int s = sb + r;
                        int pos = (((e >> 3) ^ (s & 7)) << 3) | (e & 7);
                        base[(size_t)s * 64 + pos] = __float2bfloat16(acc[mt][nt][r] + bcol);
                    }
                } else {
                    int cc = col - 2 * DD, hh = cc >> 6, e = cc & 63;
                    int c_t = sb >> 3;
                    int sc = (c_t & ~7) | ((c_t & 7) ^ (e & 7));
                    size_t off = (((size_t)bq_ * HH + hh) * 64 + e) * SS + sc * 8 + (sb & 7);
                    ushort4 pk;
                    pk.x = f2bfbits(acc[mt][nt][0] + bcol);
                    pk.y = f2bfbits(acc[mt][nt][1] + bcol);
                    pk.z = f2bfbits(acc[mt][nt][2] + bcol);
                    pk.w = f2bfbits(acc[mt][nt][3] + bcol);
                    *(ushort4*)&vtg[off] = pk;
                }
            }
        }
        return;
    }

    #pragma unroll
    for (int mt = 0; mt < MFRAG; mt++) {
        int rbase = row0 + wm + mt * 16 + quad * 4;
        #pragma unroll
        for (int nt = 0; nt < 4; nt++) {
            int col = col0 + wn + nt * 16 + l16;
            float bcol = bias[col];
            #pragma unroll
            for (int r = 0; r < 4; r++) {
                int row = rbase + r;
                float v = acc[mt][nt][r] + bcol;
                if (act) v = gelu_fast(v);
                if (residf) v += residf[(size_t)row * N + col];
                if (residb) v += __bfloat162float(residb[(size_t)row * N + col]);
                if (out_bf16) ((bf16*)Cout)[(size_t)row * N + col] = __float2bfloat16(v);
                else          ((float*)Cout)[(size_t)row * N + col] = v;
            }
        }
    }
}

// ---------------- MFMA flash attention: S^T form, no-max softmax -------------------
// setprio REVERTED (r5: total regressed +6us with GEMM dispatches identical; our
// 4-wave barrier-synced blocks are GEMM-like lockstep — m190's null/negative case).
__global__ __launch_bounds__(256) void attn_mfma(
    const bf16* __restrict__ qh, const bf16* __restrict__ kh,
    const bf16* __restrict__ vT, bf16* __restrict__ ao)
{
    __shared__ bf16 Ks[2][64 * 64];
    __shared__ bf16 Vs[2][64 * 64];
    __shared__ bf16 Ps[128 * 64];

    int tid = threadIdx.x;
    int wave = tid >> 6, lane = tid & 63;
    int l16 = lane & 15, quad = lane >> 4;
    int id = blockIdx.x;
    int bh = (id & 7) * 12 + ((id >> 3) >> 3);
    int b = bh / HH, h = bh % HH;
    int s0 = ((id >> 3) & 7) * 128;
    int wm = wave * 32;

    const bf16* qbase = qh + ((size_t)bh * SS) * HDD;
    const bf16* kbase = kh + ((size_t)bh * SS) * HDD;
    const bf16* vbase = vT + ((size_t)bh * HDD) * SS;

    auto stage = [&](int t0, int buf) {
        #pragma unroll
        for (int i = 0; i < 2; i++) {
            int c = tid + i * 256;
            gload16(kbase + (size_t)t0 * 64 + c * 8, &Ks[buf][c * 8]);
            gload16(vbase + (size_t)(c >> 3) * SS + t0 + (c & 7) * 8, &Vs[buf][c * 8]);
        }
    };

    bf16x8 qf[2][2];
    #pragma unroll
    for (int mt = 0; mt < 2; mt++)
        #pragma unroll
        for (int ks = 0; ks < 2; ks++)
            qf[mt][ks] = *(const bf16x8*)(qbase +
                (size_t)(s0 + wm + mt * 16 + l16) * HDD + ks * 32 + quad * 8);

    floatx4 oaccT[4][2] = {};
    float lsum[2] = {};

    stage(0, 0);
    int cur = 0;
    for (int t0 = 0; t0 < SS; t0 += 64) {
        __syncthreads();
        if (t0 + 64 < SS) stage(t0 + 64, cur ^ 1);

        floatx4 st[4][2] = {};
        #pragma unroll
        for (int tt = 0; tt < 4; tt++) {
            int t = tt * 16 + l16;
            #pragma unroll
            for (int ks = 0; ks < 2; ks++) {
                int pos = (quad + 4 * ks) ^ (t & 7);
                bf16x8 kf = *(const bf16x8*)(&Ks[cur][t * 64 + pos * 8]);
                #pragma unroll
                for (int mt = 0; mt < 2; mt++)
                    st[tt][mt] = __builtin_amdgcn_mfma_f32_16x16x32_bf16(
                        kf, qf[mt][ks], st[tt][mt], 0, 0, 0);
            }
        }

        #pragma unroll
        for (int tt = 0; tt < 4; tt++)
            #pragma unroll
            for (int mt = 0; mt < 2; mt++) {
                float p0 = __expf(st[tt][mt][0]);
                float p1 = __expf(st[tt][mt][1]);
                float p2 = __expf(st[tt][mt][2]);
                float p3 = __expf(st[tt][mt][3]);
                lsum[mt] += (p0 + p1) + (p2 + p3);
                int m = wm + mt * 16 + l16;
                int c = tt * 2 + (quad >> 1);
                ushort4 pk;
                pk.x = f2bfbits(p0); pk.y = f2bfbits(p1);
                pk.z = f2bfbits(p2); pk.w = f2bfbits(p3);
                *(ushort4*)&Ps[m * 64 + ((c ^ (m & 7)) << 3) + (quad & 1) * 4] = pk;
            }

        #pragma unroll
        for (int ks = 0; ks < 2; ks++) {
            bf16x8 pf[2];
            #pragma unroll
            for (int mt = 0; mt < 2; mt++) {
                int m = wm + mt * 16 + l16;
                pf[mt] = *(const bf16x8*)(&Ps[m * 64 + (((quad + 4 * ks) ^ (m & 7)) << 3)]);
            }
            #pragma unroll
            for (int et = 0; et < 4; et++) {
                int e = et * 16 + l16;
                int vpos = (quad + 4 * ks) ^ (e & 7);
                bf16x8 vf = *(const bf16x8*)(&Vs[cur][e * 64 + vpos * 8]);
                #pragma unroll
                for (int mt = 0; mt < 2; mt++)
                    oaccT[et][mt] = __builtin_amdgcn_mfma_f32_16x16x32_bf16(
                        vf, pf[mt], oaccT[et][mt], 0, 0, 0);
            }
        }
        cur ^= 1;
    }

    float linv[2];
    #pragma unroll
    for (int mt = 0; mt < 2; mt++) {
        float l = lsum[mt];
        l += __shfl_xor(l, 16, 64);
        l += __shfl_xor(l, 32, 64);
        linv[mt] = __builtin_amdgcn_rcpf(l);
    }
    #pragma unroll
    for (int et = 0; et < 4; et++)
        #pragma unroll
        for (int mt = 0; mt < 2; mt++) {
            int m = wm + mt * 16 + l16;
            int c = et * 2 + (quad >> 1);
            ushort4 pk;
            pk.x = f2bfbits(oaccT[et][mt][0] * linv[mt]);
            pk.y = f2bfbits(oaccT[et][mt][1] * linv[mt]);
            pk.z = f2bfbits(oaccT[et][mt][2] * linv[mt]);
            pk.w = f2bfbits(oaccT[et][mt][3] * linv[mt]);
            *(ushort4*)&Ps[m * 64 + ((c ^ (m & 7)) << 3) + (quad & 1) * 4] = pk;
        }
    int mrow = wm + (lane >> 1);
    bf16* op = ao + ((size_t)b * SS + s0 + mrow) * DD + h * HDD;
    #pragma unroll
    for (int i = 0; i < 4; i++) {
        int j = (lane & 1) * 4 + i;
        bf16x8 v = *(const bf16x8*)&Ps[mrow * 64 + ((j ^ (mrow & 7)) << 3)];
        *(bf16x8*)&op[j * 8] = v;
    }
}

// -----------------------------------------------------------------------------------
extern "C" void kernel_launch(void* const* d_in, const int* in_sizes, int n_in,
                              void* d_out, int out_size, void* d_ws, size_t ws_size,
                              hipStream_t stream)
{
    (void)in_sizes; (void)n_in; (void)out_size; (void)ws_size;
    const float* x    = (const float*)d_in[0];
    const float* ln1w = (const float*)d_in[1];
    const float* ln1b = (const float*)d_in[2];
    const float* Wq   = (const float*)d_in[3];
    const float* bq   = (const float*)d_in[4];
    const float* Wk   = (const float*)d_in[5];
    const float* bk   = (const float*)d_in[6];
    const float* Wv   = (const float*)d_in[7];
    const float* bv   = (const float*)d_in[8];
    const float* Wp   = (const float*)d_in[9];
    const float* bp   = (const float*)d_in[10];
    const float* ln2w = (const float*)d_in[11];
    const float* ln2b = (const float*)d_in[12];
    const float* W1   = (const float*)d_in[13];
    const float* b1   = (const float*)d_in[14];
    const float* W2   = (const float*)d_in[15];
    const float* b2   = (const float*)d_in[16];
    float* out = (float*)d_out;

    char* p = (char*)d_ws;
    auto alloc = [&](size_t bytes) { char* r = p; p += (bytes + 255) & ~255ull; return r; };
    bf16*  Wqkvt = (bf16*)alloc((size_t)QKVN * DD * 2);
    bf16*  Wpt   = (bf16*)alloc((size_t)DD * DD * 2);
    bf16*  W1t   = (bf16*)alloc((size_t)FFF * DD * 2);
    bf16*  W2t   = (bf16*)alloc((size_t)DD * FFF * 2);
    float* bqkv  = (float*)alloc((size_t)QKVN * 4);
    bf16*  yb    = (bf16*)alloc((size_t)NROW * DD * 2);
    bf16*  x1b   = (bf16*)alloc((size_t)NROW * DD * 2);        // residual stream 1, bf16
    char*  dynr  = alloc((size_t)NROW * DD * 2 + 3 * ((size_t)NROW * DD * 2));
    bf16*  aob   = (bf16*)dynr;                                // [row][768]
    bf16*  qhb   = (bf16*)(dynr + (size_t)NROW * DD * 2);      // [bh][s][64]
    bf16*  khb   = qhb + (size_t)NROW * DD;                    // swizzled
    bf16*  vtb   = khb + (size_t)NROW * DD;                    // [bh][e][1024] swizzled
    bf16*  hb    = (bf16*)dynr;   // FF intermediate (50MB) reuses aob+qkv region

    prep_kernel<<<6915, 256, 0, stream>>>(Wq, Wk, Wv, Wp, W1, W2, bq, bk, bv,
                                          Wqkvt, Wpt, W1t, W2t, bqkv);

    ln_kernel<float><<<NROW/4, 256, 0, stream>>>(x, ln1w, ln1b, yb);

    // fused QKV GEMM, head-separating scatter (MT=128 DEPTH=3 control)
    mfma_gemm<128,1,3><<<1152, 256, 0, stream>>>(
        yb, Wqkvt, bqkv, nullptr, nullptr, nullptr, NROW, QKVN, DD, 0, 0, 18, 8,
        1, qhb, khb, vtb);

    attn_mfma<<<dim3(BB*HH*(SS/128)), 256, 0, stream>>>(qhb, khb, vtb, aob);

    // projection + GELU + residual(x fp32) -> x1 bf16  (MT=64 DEPTH=2 control)
    mfma_gemm<64,2,2><<<768, 256, 0, stream>>>(
        aob, Wpt, bp, x, nullptr, x1b, NROW, DD, DD, 1, 1, 6, 16,
        0, nullptr, nullptr, nullptr);

    ln_kernel<bf16><<<NROW/4, 256, 0, stream>>>(x1b, ln2w, ln2b, yb);

    // FF1 + GELU -> hb bf16  (MT=64 KH=1: 24KB LDS -> 6 blocks/CU, 24 waves/CU.
    // Occupancy test: LDS was the cap at 48KB/3 blocks across all r2-r5 configs)
    mfma_gemm<64,1,2><<<3072, 256, 0, stream>>>(
        yb, W1t, b1, nullptr, nullptr, hb, NROW, FFF, DD, 1, 1, 24, 16,
        0, nullptr, nullptr, nullptr);

    // FF2 + GELU + residual(x1 bf16) -> out fp32  (MT=64 DEPTH=2 control)
    mfma_gemm<64,2,2><<<768, 256, 0, stream>>>(
        hb, W2t, b2, nullptr, x1b, out, NROW, DD, FFF, 1, 0, 6, 16,
        0, nullptr, nullptr, nullptr);
}

// Round 7
// 368.908 us; speedup vs baseline: 1.0243x; 1.0243x over previous
//
#include <hip/hip_runtime.h>
#include <hip/hip_bf16.h>
#include <math.h>

#define BB 8
#define SS 1024
#define DD 768
#define HH 12
#define HDD 64
#define FFF 3072
#define NROW (BB*SS)
#define QKVN (3*DD)

typedef __hip_bfloat16 bf16;
typedef __bf16 bf16x8 __attribute__((ext_vector_type(8)));
typedef float floatx4 __attribute__((ext_vector_type(4)));

// tanh-form GELU: ~9 VALU ops (exp+rcp) vs ~30 for erff; max abs err ~1e-3.
__device__ __forceinline__ float gelu_fast(float x) {
    float u = x * fmaf(0.07135481627f, x * x, 1.595769122f);
    float e = __expf(u);
    return x * e * __builtin_amdgcn_rcpf(e + 1.0f);
}

__device__ __forceinline__ unsigned short f2bfbits(float f) {
    bf16 h = __float2bfloat16(f);
    return __builtin_bit_cast(unsigned short, h);
}

__device__ __forceinline__ void gload16(const void* g, void* l) {
    __builtin_amdgcn_global_load_lds(
        (const __attribute__((address_space(1))) unsigned int*)g,
        (__attribute__((address_space(3))) unsigned int*)l, 16, 0, 0);
}

// ---------------- LayerNorm: one WAVE per row, vectorized, zero barriers -----------
template<typename T>
__global__ __launch_bounds__(256) void ln_kernel(const T* __restrict__ x,
                                                 const float* __restrict__ w,
                                                 const float* __restrict__ b,
                                                 bf16* __restrict__ y) {
    int wave = threadIdx.x >> 6, lane = threadIdx.x & 63;
    int row = blockIdx.x * 4 + wave;
    const T* xr = x + (size_t)row * DD;
    bf16* yr = y + (size_t)row * DD;

    float v[12];
    #pragma unroll
    for (int s = 0; s < 3; s++) {
        int base = s * 256 + lane * 4;
        if constexpr (__is_same(T, float)) {
            float4 f = *(const float4*)(xr + base);
            v[s*4+0] = f.x; v[s*4+1] = f.y; v[s*4+2] = f.z; v[s*4+3] = f.w;
        } else {
            ushort4 u = *(const ushort4*)(xr + base);
            v[s*4+0] = __bfloat162float(__builtin_bit_cast(bf16, u.x));
            v[s*4+1] = __bfloat162float(__builtin_bit_cast(bf16, u.y));
            v[s*4+2] = __bfloat162float(__builtin_bit_cast(bf16, u.z));
            v[s*4+3] = __bfloat162float(__builtin_bit_cast(bf16, u.w));
        }
    }
    float sum = 0.f, sq = 0.f;
    #pragma unroll
    for (int i = 0; i < 12; i++) { sum += v[i]; sq += v[i] * v[i]; }
    #pragma unroll
    for (int off = 1; off < 64; off <<= 1) {
        sum += __shfl_xor(sum, off, 64);
        sq  += __shfl_xor(sq,  off, 64);
    }
    float mu  = sum * (1.0f / DD);
    float var = sq * (1.0f / DD) - mu * mu;
    float inv = rsqrtf(var + 1e-5f);

    #pragma unroll
    for (int s = 0; s < 3; s++) {
        int base = s * 256 + lane * 4;
        float4 wf = *(const float4*)(w + base);
        float4 bf = *(const float4*)(b + base);
        ushort4 o;
        o.x = f2bfbits((v[s*4+0] - mu) * inv * wf.x + bf.x);
        o.y = f2bfbits((v[s*4+1] - mu) * inv * wf.y + bf.y);
        o.z = f2bfbits((v[s*4+2] - mu) * inv * wf.z + bf.z);
        o.w = f2bfbits((v[s*4+3] - mu) * inv * wf.w + bf.w);
        *(ushort4*)(yr + base) = o;
    }
}

// ------------- fused weight prep: all transposes+casts + bias concat, ONE launch ---
__global__ __launch_bounds__(256) void prep_kernel(
    const float* __restrict__ Wq, const float* __restrict__ Wk,
    const float* __restrict__ Wv, const float* __restrict__ Wp,
    const float* __restrict__ W1, const float* __restrict__ W2,
    const float* __restrict__ bq, const float* __restrict__ bk,
    const float* __restrict__ bv,
    bf16* __restrict__ Wqkvt, bf16* __restrict__ Wpt,
    bf16* __restrict__ W1t, bf16* __restrict__ W2t, float* __restrict__ bqkv)
{
    int id = blockIdx.x;
    if (id >= 6912) {
        int i = (id - 6912) * 256 + threadIdx.x;
        if (i < DD) { bqkv[i] = bq[i]; bqkv[DD + i] = bk[i]; bqkv[2*DD + i] = bv[i]; }
        return;
    }
    const float* src; bf16* dst; int K, N, hmode, local;
    if (id < 1728)      { K = DD;  N = DD;  hmode = 1; local = id % 576;
                          src = (id < 576) ? Wq : (id < 1152 ? Wk : Wv);
                          dst = Wqkvt + (size_t)(id / 576) * DD * DD; }
    else if (id < 2304) { K = DD;  N = DD;  hmode = 0; local = id - 1728; src = Wp; dst = Wpt; }
    else if (id < 4608) { K = DD;  N = FFF; hmode = 0; local = id - 2304; src = W1; dst = W1t; }
    else                { K = FFF; N = DD;  hmode = 0; local = id - 4608; src = W2; dst = W2t; }
    int ktiles = K / 32;
    int k0 = (local % ktiles) * 32, n0 = (local / ktiles) * 32;
    __shared__ float t[32][33];
    int tx = threadIdx.x & 31, ty4 = threadIdx.x >> 5;
    #pragma unroll
    for (int i = 0; i < 4; i++) {
        int k = k0 + ty4 * 4 + i;
        int n = n0 + tx;
        size_t si = hmode ? ((size_t)(n >> 6) * K * 64 + (size_t)k * 64 + (n & 63))
                          : ((size_t)k * N + n);
        t[ty4 * 4 + i][tx] = src[si];
    }
    __syncthreads();
    #pragma unroll
    for (int i = 0; i < 4; i++) {
        int n = n0 + ty4 * 4 + i;
        int k = k0 + tx;
        dst[(size_t)n * K + k] = __float2bfloat16(t[tx][ty4 * 4 + i]);
    }
}

// ---------------- MFMA bf16 GEMM: C = epi(A @ Bt^T) --------------------------------
// 1D grid, XCD-cooperative: xcd = id&7 owns `py` row-panels x `nx` col tiles.
// COLUMN-MAJOR slot order (r7): rp = slot%py, ct = slot/py — an XCD's ~96
// concurrent blocks span few col-tiles x many row-panels, so the L2 working set is
// ~6 B-tiles + 16 A-panels (~2.8MB < 4MB) instead of ALL B (5.1MB, thrash).
// r5 FETCH showed B re-fetched ~14x from HBM (81MB vs 17MB ideal) -> HBM-miss
// latency (~900cy vs L2 ~200cy, m126) on the barrier-exposed stage path.
// MEASURED (r2-r6): dur invariant to MT(64/128), KH(1/2), DEPTH(2/3), occupancy
// (3 vs 6 blocks/CU) — FF1 floor 73.0us. L2 residency is the untested axis.
template<int MT, int KH, int DEPTH>
__global__ __launch_bounds__(256) void mfma_gemm(
    const bf16* __restrict__ A, const bf16* __restrict__ Bt,
    const float* __restrict__ bias, const float* __restrict__ residf,
    const bf16* __restrict__ residb, void* __restrict__ Cout,
    int M, int N, int K, int act, int out_bf16, int nx, int py,
    int qkvmode, bf16* __restrict__ qhg, bf16* __restrict__ khg, bf16* __restrict__ vtg)
{
    constexpr int MFRAG = MT / 32;
    constexpr int ACH = MT * 4;
    constexpr int LOADS = ACH * KH / 256 + 2 * KH;   // gload16 per thread per stage
    static_assert(DEPTH == 2 || (DEPTH == 3 && LOADS == 4), "vmcnt literal fixed at 4");
    __shared__ bf16 As[DEPTH][KH * MT * 32];
    __shared__ bf16 Bs[DEPTH][KH * 128 * 32];
    int tid = threadIdx.x;
    int id = blockIdx.x;
    int xcd = id & 7, slot = id >> 3;
    int rp = slot % py, ct = slot / py;          // col-major within XCD (L2 blocking)
    int row0 = (xcd * py + rp) * MT, col0 = ct * 128;
    int wave = tid >> 6, lane = tid & 63;
    int wm = (wave >> 1) * (MT / 2), wn = (wave & 1) * 64;
    int l16 = lane & 15, quad = lane >> 4;

    auto stage = [&](int k0, int buf) {
        #pragma unroll
        for (int i = 0; i < ACH * KH / 256; i++) {
            int c = tid + i * 256;
            int half = c / ACH, rem = c % ACH;
            int r = rem >> 2, pos = rem & 3;
            int ksw = k0 + half * 32 + ((pos ^ ((r >> 1) & 3)) << 3);
            gload16(A + (size_t)(row0 + r) * K + ksw, &As[buf][c * 8]);
        }
        #pragma unroll
        for (int i = 0; i < 2 * KH; i++) {
            int c = tid + i * 256;
            int half = c >> 9, rem = c & 511;
            int r = rem >> 2, pos = rem & 3;
            int ksw = k0 + half * 32 + ((pos ^ ((r >> 1) & 3)) << 3);
            gload16(Bt + (size_t)(col0 + r) * K + ksw, &Bs[buf][c * 8]);
        }
    };

    floatx4 acc[MFRAG][4] = {};

    auto compute = [&](int cur) {
        #pragma unroll
        for (int s = 0; s < KH; s++) {
            bf16x8 af[MFRAG], bfr[4];
            #pragma unroll
            for (int mt = 0; mt < MFRAG; mt++) {
                int r = wm + mt * 16 + l16;
                int pos = quad ^ ((r >> 1) & 3);
                af[mt] = *(const bf16x8*)&As[cur][s * MT * 32 + r * 32 + pos * 8];
            }
            #pragma unroll
            for (int nt = 0; nt < 4; nt++) {
                int r = wn + nt * 16 + l16;
                int pos = quad ^ ((r >> 1) & 3);
                bfr[nt] = *(const bf16x8*)&Bs[cur][s * 4096 + r * 32 + pos * 8];
            }
            #pragma unroll
            for (int mt = 0; mt < MFRAG; mt++)
                #pragma unroll
                for (int nt = 0; nt < 4; nt++)
                    acc[mt][nt] = __builtin_amdgcn_mfma_f32_16x16x32_bf16(
                        af[mt], bfr[nt], acc[mt][nt], 0, 0, 0);
        }
    };

    if constexpr (DEPTH == 3) {
        int T = K / (32 * KH);
        stage(0, 0);
        if (T > 1) stage(32 * KH, 1);
        for (int t = 0; t < T; t++) {
            if (t == T - 1) { asm volatile("s_waitcnt vmcnt(0)" ::: "memory"); }
            else            { asm volatile("s_waitcnt vmcnt(4)" ::: "memory"); }
            __builtin_amdgcn_s_barrier();
            if (t + 2 < T) stage((t + 2) * (32 * KH), (t + 2) % 3);
            compute(t % 3);
        }
    } else {
        stage(0, 0);
        int cur = 0;
        for (int k0 = 0; k0 < K; k0 += 32 * KH) {
            __syncthreads();
            if (k0 + 32 * KH < K) stage(k0 + 32 * KH, cur ^ 1);
            compute(cur);
            cur ^= 1;
        }
    }

    if (qkvmode) {
        #pragma unroll
        for (int mt = 0; mt < MFRAG; mt++) {
            int rbase = row0 + wm + mt * 16 + quad * 4;
            int bq_ = rbase >> 10, sb = rbase & 1023;
            #pragma unroll
            for (int nt = 0; nt < 4; nt++) {
                int col = col0 + wn + nt * 16 + l16;
                float bcol = bias[col];
                if (col < DD) {
                    int hh = col >> 6, e = col & 63;
                    bf16* base = qhg + (((size_t)bq_ * HH + hh) * SS + sb) * 64 + e;
                    #pragma unroll
                    for (int r = 0; r < 4; r++)
                        base[(size_t)r * 64] = __float2bfloat16(acc[mt][nt][r] + bcol);
                } else if (col < 2 * DD) {
                    int cc = col - DD, hh = cc >> 6, e = cc & 63;
                    bf16* base = khg + (((size_t)bq_ * HH + hh) * SS) * 64;
                    #pragma unroll
                    for (int r = 0; r < 4; r++) {
                        int s = sb + r;
                        int pos = (((e >> 3) ^ (s & 7)) << 3) | (e & 7);
                        base[(size_t)s * 64 + pos] = __float2bfloat16(acc[mt][nt][r] + bcol);
                    }
                } else {
                    int cc = col - 2 * DD, hh = cc >> 6, e = cc & 63;
                    int c_t = sb >> 3;
                    int sc = (c_t & ~7) | ((c_t & 7) ^ (e & 7));
                    size_t off = (((size_t)bq_ * HH + hh) * 64 + e) * SS + sc * 8 + (sb & 7);
                    ushort4 pk;
                    pk.x = f2bfbits(acc[mt][nt][0] + bcol);
                    pk.y = f2bfbits(acc[mt][nt][1] + bcol);
                    pk.z = f2bfbits(acc[mt][nt][2] + bcol);
                    pk.w = f2bfbits(acc[mt][nt][3] + bcol);
                    *(ushort4*)&vtg[off] = pk;
                }
            }
        }
        return;
    }

    #pragma unroll
    for (int mt = 0; mt < MFRAG; mt++) {
        int rbase = row0 + wm + mt * 16 + quad * 4;
        #pragma unroll
        for (int nt = 0; nt < 4; nt++) {
            int col = col0 + wn + nt * 16 + l16;
            float bcol = bias[col];
            #pragma unroll
            for (int r = 0; r < 4; r++) {
                int row = rbase + r;
                float v = acc[mt][nt][r] + bcol;
                if (act) v = gelu_fast(v);
                if (residf) v += residf[(size_t)row * N + col];
                if (residb) v += __bfloat162float(residb[(size_t)row * N + col]);
                if (out_bf16) ((bf16*)Cout)[(size_t)row * N + col] = __float2bfloat16(v);
                else          ((float*)Cout)[(size_t)row * N + col] = v;
            }
        }
    }
}

// ---------------- MFMA flash attention: S^T form, no-max softmax -------------------
// setprio reverted (r5: m190's lockstep-negative case applies to our 4-wave blocks).
__global__ __launch_bounds__(256) void attn_mfma(
    const bf16* __restrict__ qh, const bf16* __restrict__ kh,
    const bf16* __restrict__ vT, bf16* __restrict__ ao)
{
    __shared__ bf16 Ks[2][64 * 64];
    __shared__ bf16 Vs[2][64 * 64];
    __shared__ bf16 Ps[128 * 64];

    int tid = threadIdx.x;
    int wave = tid >> 6, lane = tid & 63;
    int l16 = lane & 15, quad = lane >> 4;
    int id = blockIdx.x;
    int bh = (id & 7) * 12 + ((id >> 3) >> 3);
    int b = bh / HH, h = bh % HH;
    int s0 = ((id >> 3) & 7) * 128;
    int wm = wave * 32;

    const bf16* qbase = qh + ((size_t)bh * SS) * HDD;
    const bf16* kbase = kh + ((size_t)bh * SS) * HDD;
    const bf16* vbase = vT + ((size_t)bh * HDD) * SS;

    auto stage = [&](int t0, int buf) {
        #pragma unroll
        for (int i = 0; i < 2; i++) {
            int c = tid + i * 256;
            gload16(kbase + (size_t)t0 * 64 + c * 8, &Ks[buf][c * 8]);
            gload16(vbase + (size_t)(c >> 3) * SS + t0 + (c & 7) * 8, &Vs[buf][c * 8]);
        }
    };

    bf16x8 qf[2][2];
    #pragma unroll
    for (int mt = 0; mt < 2; mt++)
        #pragma unroll
        for (int ks = 0; ks < 2; ks++)
            qf[mt][ks] = *(const bf16x8*)(qbase +
                (size_t)(s0 + wm + mt * 16 + l16) * HDD + ks * 32 + quad * 8);

    floatx4 oaccT[4][2] = {};
    float lsum[2] = {};

    stage(0, 0);
    int cur = 0;
    for (int t0 = 0; t0 < SS; t0 += 64) {
        __syncthreads();
        if (t0 + 64 < SS) stage(t0 + 64, cur ^ 1);

        floatx4 st[4][2] = {};
        #pragma unroll
        for (int tt = 0; tt < 4; tt++) {
            int t = tt * 16 + l16;
            #pragma unroll
            for (int ks = 0; ks < 2; ks++) {
                int pos = (quad + 4 * ks) ^ (t & 7);
                bf16x8 kf = *(const bf16x8*)(&Ks[cur][t * 64 + pos * 8]);
                #pragma unroll
                for (int mt = 0; mt < 2; mt++)
                    st[tt][mt] = __builtin_amdgcn_mfma_f32_16x16x32_bf16(
                        kf, qf[mt][ks], st[tt][mt], 0, 0, 0);
            }
        }

        #pragma unroll
        for (int tt = 0; tt < 4; tt++)
            #pragma unroll
            for (int mt = 0; mt < 2; mt++) {
                float p0 = __expf(st[tt][mt][0]);
                float p1 = __expf(st[tt][mt][1]);
                float p2 = __expf(st[tt][mt][2]);
                float p3 = __expf(st[tt][mt][3]);
                lsum[mt] += (p0 + p1) + (p2 + p3);
                int m = wm + mt * 16 + l16;
                int c = tt * 2 + (quad >> 1);
                ushort4 pk;
                pk.x = f2bfbits(p0); pk.y = f2bfbits(p1);
                pk.z = f2bfbits(p2); pk.w = f2bfbits(p3);
                *(ushort4*)&Ps[m * 64 + ((c ^ (m & 7)) << 3) + (quad & 1) * 4] = pk;
            }

        #pragma unroll
        for (int ks = 0; ks < 2; ks++) {
            bf16x8 pf[2];
            #pragma unroll
            for (int mt = 0; mt < 2; mt++) {
                int m = wm + mt * 16 + l16;
                pf[mt] = *(const bf16x8*)(&Ps[m * 64 + (((quad + 4 * ks) ^ (m & 7)) << 3)]);
            }
            #pragma unroll
            for (int et = 0; et < 4; et++) {
                int e = et * 16 + l16;
                int vpos = (quad + 4 * ks) ^ (e & 7);
                bf16x8 vf = *(const bf16x8*)(&Vs[cur][e * 64 + vpos * 8]);
                #pragma unroll
                for (int mt = 0; mt < 2; mt++)
                    oaccT[et][mt] = __builtin_amdgcn_mfma_f32_16x16x32_bf16(
                        vf, pf[mt], oaccT[et][mt], 0, 0, 0);
            }
        }
        cur ^= 1;
    }

    float linv[2];
    #pragma unroll
    for (int mt = 0; mt < 2; mt++) {
        float l = lsum[mt];
        l += __shfl_xor(l, 16, 64);
        l += __shfl_xor(l, 32, 64);
        linv[mt] = __builtin_amdgcn_rcpf(l);
    }
    #pragma unroll
    for (int et = 0; et < 4; et++)
        #pragma unroll
        for (int mt = 0; mt < 2; mt++) {
            int m = wm + mt * 16 + l16;
            int c = et * 2 + (quad >> 1);
            ushort4 pk;
            pk.x = f2bfbits(oaccT[et][mt][0] * linv[mt]);
            pk.y = f2bfbits(oaccT[et][mt][1] * linv[mt]);
            pk.z = f2bfbits(oaccT[et][mt][2] * linv[mt]);
            pk.w = f2bfbits(oaccT[et][mt][3] * linv[mt]);
            *(ushort4*)&Ps[m * 64 + ((c ^ (m & 7)) << 3) + (quad & 1) * 4] = pk;
        }
    int mrow = wm + (lane >> 1);
    bf16* op = ao + ((size_t)b * SS + s0 + mrow) * DD + h * HDD;
    #pragma unroll
    for (int i = 0; i < 4; i++) {
        int j = (lane & 1) * 4 + i;
        bf16x8 v = *(const bf16x8*)&Ps[mrow * 64 + ((j ^ (mrow & 7)) << 3)];
        *(bf16x8*)&op[j * 8] = v;
    }
}

// -----------------------------------------------------------------------------------
extern "C" void kernel_launch(void* const* d_in, const int* in_sizes, int n_in,
                              void* d_out, int out_size, void* d_ws, size_t ws_size,
                              hipStream_t stream)
{
    (void)in_sizes; (void)n_in; (void)out_size; (void)ws_size;
    const float* x    = (const float*)d_in[0];
    const float* ln1w = (const float*)d_in[1];
    const float* ln1b = (const float*)d_in[2];
    const float* Wq   = (const float*)d_in[3];
    const float* bq   = (const float*)d_in[4];
    const float* Wk   = (const float*)d_in[5];
    const float* bk   = (const float*)d_in[6];
    const float* Wv   = (const float*)d_in[7];
    const float* bv   = (const float*)d_in[8];
    const float* Wp   = (const float*)d_in[9];
    const float* bp   = (const float*)d_in[10];
    const float* ln2w = (const float*)d_in[11];
    const float* ln2b = (const float*)d_in[12];
    const float* W1   = (const float*)d_in[13];
    const float* b1   = (const float*)d_in[14];
    const float* W2   = (const float*)d_in[15];
    const float* b2   = (const float*)d_in[16];
    float* out = (float*)d_out;

    char* p = (char*)d_ws;
    auto alloc = [&](size_t bytes) { char* r = p; p += (bytes + 255) & ~255ull; return r; };
    bf16*  Wqkvt = (bf16*)alloc((size_t)QKVN * DD * 2);
    bf16*  Wpt   = (bf16*)alloc((size_t)DD * DD * 2);
    bf16*  W1t   = (bf16*)alloc((size_t)FFF * DD * 2);
    bf16*  W2t   = (bf16*)alloc((size_t)DD * FFF * 2);
    float* bqkv  = (float*)alloc((size_t)QKVN * 4);
    bf16*  yb    = (bf16*)alloc((size_t)NROW * DD * 2);
    bf16*  x1b   = (bf16*)alloc((size_t)NROW * DD * 2);        // residual stream 1, bf16
    char*  dynr  = alloc((size_t)NROW * DD * 2 + 3 * ((size_t)NROW * DD * 2));
    bf16*  aob   = (bf16*)dynr;                                // [row][768]
    bf16*  qhb   = (bf16*)(dynr + (size_t)NROW * DD * 2);      // [bh][s][64]
    bf16*  khb   = qhb + (size_t)NROW * DD;                    // swizzled
    bf16*  vtb   = khb + (size_t)NROW * DD;                    // [bh][e][1024] swizzled
    bf16*  hb    = (bf16*)dynr;   // FF intermediate (50MB) reuses aob+qkv region

    prep_kernel<<<6915, 256, 0, stream>>>(Wq, Wk, Wv, Wp, W1, W2, bq, bk, bv,
                                          Wqkvt, Wpt, W1t, W2t, bqkv);

    ln_kernel<float><<<NROW/4, 256, 0, stream>>>(x, ln1w, ln1b, yb);

    // fused QKV GEMM, head-separating scatter (MT=128 DEPTH=3, col-major slots)
    mfma_gemm<128,1,3><<<1152, 256, 0, stream>>>(
        yb, Wqkvt, bqkv, nullptr, nullptr, nullptr, NROW, QKVN, DD, 0, 0, 18, 8,
        1, qhb, khb, vtb);

    attn_mfma<<<dim3(BB*HH*(SS/128)), 256, 0, stream>>>(qhb, khb, vtb, aob);

    // projection + GELU + residual(x fp32) -> x1 bf16  (MT=64 DEPTH=2)
    mfma_gemm<64,2,2><<<768, 256, 0, stream>>>(
        aob, Wpt, bp, x, nullptr, x1b, NROW, DD, DD, 1, 1, 6, 16,
        0, nullptr, nullptr, nullptr);

    ln_kernel<bf16><<<NROW/4, 256, 0, stream>>>(x1b, ln2w, ln2b, yb);

    // FF1 + GELU -> hb bf16  (REVERTED to best-known MT=64/KH=2/DEPTH=2; col-major
    // slots: concurrent blocks share ~6 B col-tiles -> B stays L2-resident)
    mfma_gemm<64,2,2><<<3072, 256, 0, stream>>>(
        yb, W1t, b1, nullptr, nullptr, hb, NROW, FFF, DD, 1, 1, 24, 16,
        0, nullptr, nullptr, nullptr);

    // FF2 + GELU + residual(x1 bf16) -> out fp32  (MT=64 DEPTH=2, col-major slots)
    mfma_gemm<64,2,2><<<768, 256, 0, stream>>>(
        hb, W2t, b2, nullptr, x1b, out, NROW, DD, FFF, 1, 0, 6, 16,
        0, nullptr, nullptr, nullptr);
}

// Round 8
// 364.509 us; speedup vs baseline: 1.0366x; 1.0121x over previous
//
#include <hip/hip_runtime.h>
#include <hip/hip_bf16.h>
#include <math.h>

#define BB 8
#define SS 1024
#define DD 768
#define HH 12
#define HDD 64
#define FFF 3072
#define NROW (BB*SS)
#define QKVN (3*DD)

typedef __hip_bfloat16 bf16;
typedef __bf16 bf16x8 __attribute__((ext_vector_type(8)));
typedef float floatx4 __attribute__((ext_vector_type(4)));

// tanh-form GELU: ~9 VALU ops (exp+rcp) vs ~30 for erff; max abs err ~1e-3.
__device__ __forceinline__ float gelu_fast(float x) {
    float u = x * fmaf(0.07135481627f, x * x, 1.595769122f);
    float e = __expf(u);
    return x * e * __builtin_amdgcn_rcpf(e + 1.0f);
}

__device__ __forceinline__ unsigned short f2bfbits(float f) {
    bf16 h = __float2bfloat16(f);
    return __builtin_bit_cast(unsigned short, h);
}

__device__ __forceinline__ void gload16(const void* g, void* l) {
    __builtin_amdgcn_global_load_lds(
        (const __attribute__((address_space(1))) unsigned int*)g,
        (__attribute__((address_space(3))) unsigned int*)l, 16, 0, 0);
}

// ---------------- LayerNorm: one WAVE per row, vectorized, zero barriers -----------
template<typename T>
__global__ __launch_bounds__(256) void ln_kernel(const T* __restrict__ x,
                                                 const float* __restrict__ w,
                                                 const float* __restrict__ b,
                                                 bf16* __restrict__ y) {
    int wave = threadIdx.x >> 6, lane = threadIdx.x & 63;
    int row = blockIdx.x * 4 + wave;
    const T* xr = x + (size_t)row * DD;
    bf16* yr = y + (size_t)row * DD;

    float v[12];
    #pragma unroll
    for (int s = 0; s < 3; s++) {
        int base = s * 256 + lane * 4;
        if constexpr (__is_same(T, float)) {
            float4 f = *(const float4*)(xr + base);
            v[s*4+0] = f.x; v[s*4+1] = f.y; v[s*4+2] = f.z; v[s*4+3] = f.w;
        } else {
            ushort4 u = *(const ushort4*)(xr + base);
            v[s*4+0] = __bfloat162float(__builtin_bit_cast(bf16, u.x));
            v[s*4+1] = __bfloat162float(__builtin_bit_cast(bf16, u.y));
            v[s*4+2] = __bfloat162float(__builtin_bit_cast(bf16, u.z));
            v[s*4+3] = __bfloat162float(__builtin_bit_cast(bf16, u.w));
        }
    }
    float sum = 0.f, sq = 0.f;
    #pragma unroll
    for (int i = 0; i < 12; i++) { sum += v[i]; sq += v[i] * v[i]; }
    #pragma unroll
    for (int off = 1; off < 64; off <<= 1) {
        sum += __shfl_xor(sum, off, 64);
        sq  += __shfl_xor(sq,  off, 64);
    }
    float mu  = sum * (1.0f / DD);
    float var = sq * (1.0f / DD) - mu * mu;
    float inv = rsqrtf(var + 1e-5f);

    #pragma unroll
    for (int s = 0; s < 3; s++) {
        int base = s * 256 + lane * 4;
        float4 wf = *(const float4*)(w + base);
        float4 bf = *(const float4*)(b + base);
        ushort4 o;
        o.x = f2bfbits((v[s*4+0] - mu) * inv * wf.x + bf.x);
        o.y = f2bfbits((v[s*4+1] - mu) * inv * wf.y + bf.y);
        o.z = f2bfbits((v[s*4+2] - mu) * inv * wf.z + bf.z);
        o.w = f2bfbits((v[s*4+3] - mu) * inv * wf.w + bf.w);
        *(ushort4*)(yr + base) = o;
    }
}

// ------------- fused weight prep: all transposes+casts + bias concat, ONE launch ---
__global__ __launch_bounds__(256) void prep_kernel(
    const float* __restrict__ Wq, const float* __restrict__ Wk,
    const float* __restrict__ Wv, const float* __restrict__ Wp,
    const float* __restrict__ W1, const float* __restrict__ W2,
    const float* __restrict__ bq, const float* __restrict__ bk,
    const float* __restrict__ bv,
    bf16* __restrict__ Wqkvt, bf16* __restrict__ Wpt,
    bf16* __restrict__ W1t, bf16* __restrict__ W2t, float* __restrict__ bqkv)
{
    int id = blockIdx.x;
    if (id >= 6912) {
        int i = (id - 6912) * 256 + threadIdx.x;
        if (i < DD) { bqkv[i] = bq[i]; bqkv[DD + i] = bk[i]; bqkv[2*DD + i] = bv[i]; }
        return;
    }
    const float* src; bf16* dst; int K, N, hmode, local;
    if (id < 1728)      { K = DD;  N = DD;  hmode = 1; local = id % 576;
                          src = (id < 576) ? Wq : (id < 1152 ? Wk : Wv);
                          dst = Wqkvt + (size_t)(id / 576) * DD * DD; }
    else if (id < 2304) { K = DD;  N = DD;  hmode = 0; local = id - 1728; src = Wp; dst = Wpt; }
    else if (id < 4608) { K = DD;  N = FFF; hmode = 0; local = id - 2304; src = W1; dst = W1t; }
    else                { K = FFF; N = DD;  hmode = 0; local = id - 4608; src = W2; dst = W2t; }
    int ktiles = K / 32;
    int k0 = (local % ktiles) * 32, n0 = (local / ktiles) * 32;
    __shared__ float t[32][33];
    int tx = threadIdx.x & 31, ty4 = threadIdx.x >> 5;
    #pragma unroll
    for (int i = 0; i < 4; i++) {
        int k = k0 + ty4 * 4 + i;
        int n = n0 + tx;
        size_t si = hmode ? ((size_t)(n >> 6) * K * 64 + (size_t)k * 64 + (n & 63))
                          : ((size_t)k * N + n);
        t[ty4 * 4 + i][tx] = src[si];
    }
    __syncthreads();
    #pragma unroll
    for (int i = 0; i < 4; i++) {
        int n = n0 + ty4 * 4 + i;
        int k = k0 + tx;
        dst[(size_t)n * K + k] = __float2bfloat16(t[tx][ty4 * 4 + i]);
    }
}

// ---------------- MFMA bf16 GEMM: C = epi(A @ Bt^T) --------------------------------
// 1D grid, XCD-cooperative, COL-MAJOR slot order within XCD (r7: B stays L2-resident,
// FETCH 81->29.5MB measured). LDS chunk-XOR-swizzled (BANK_CONFLICT = 0).
// r8: ALL loop addressing hoisted out of the K-loop. The m97-family asm emits ~21
// v_lshl_add_u64 per K-iter recomputing global/LDS addresses (matches VALUBusy 32% ~
// 130cy/interval vs MFMA 78cy). Precompute per-thread src pointers + LDS byte
// offsets once; in-loop addressing = base + cur*BUFBYTES + const (uniform k0 add).
// MEASURED (r2-r7): dur invariant to MT, KH, DEPTH, occupancy, L2-residency.
template<int MT, int KH, int DEPTH>
__global__ __launch_bounds__(256) void mfma_gemm(
    const bf16* __restrict__ A, const bf16* __restrict__ Bt,
    const float* __restrict__ bias, const float* __restrict__ residf,
    const bf16* __restrict__ residb, void* __restrict__ Cout,
    int M, int N, int K, int act, int out_bf16, int nx, int py,
    int qkvmode, bf16* __restrict__ qhg, bf16* __restrict__ khg, bf16* __restrict__ vtg)
{
    constexpr int MFRAG = MT / 32;
    constexpr int ACH = MT * 4;
    constexpr int A_LOADS = ACH * KH / 256;
    constexpr int B_LOADS = 2 * KH;
    constexpr int LOADS = A_LOADS + B_LOADS;
    constexpr unsigned ABYTES = KH * MT * 32 * 2;    // bytes per A buffer
    constexpr unsigned BBYTES = KH * 128 * 32 * 2;   // bytes per B buffer
    static_assert(DEPTH == 2 || (DEPTH == 3 && LOADS == 4), "vmcnt literal fixed at 4");
    __shared__ bf16 As[DEPTH][KH * MT * 32];
    __shared__ bf16 Bs[DEPTH][KH * 128 * 32];
    int tid = threadIdx.x;
    int id = blockIdx.x;
    int xcd = id & 7, slot = id >> 3;
    int rp = slot % py, ct = slot / py;          // col-major within XCD (L2 blocking)
    int row0 = (xcd * py + rp) * MT, col0 = ct * 128;
    int wave = tid >> 6, lane = tid & 63;
    int wm = (wave >> 1) * (MT / 2), wn = (wave & 1) * 64;
    int l16 = lane & 15, quad = lane >> 4;

    // ---- hoisted staging addresses (per-thread, loop-invariant) ----
    const bf16* pA[A_LOADS]; unsigned ldA[A_LOADS];
    #pragma unroll
    for (int i = 0; i < A_LOADS; i++) {
        int c = tid + i * 256;
        int half = c / ACH, rem = c % ACH;
        int r = rem >> 2, pos = rem & 3;
        int ksw = half * 32 + ((pos ^ ((r >> 1) & 3)) << 3);
        pA[i] = A + (size_t)(row0 + r) * K + ksw;
        ldA[i] = (unsigned)c * 16u;
    }
    const bf16* pB[B_LOADS]; unsigned ldB[B_LOADS];
    #pragma unroll
    for (int i = 0; i < B_LOADS; i++) {
        int c = tid + i * 256;
        int half = c >> 9, rem = c & 511;
        int r = rem >> 2, pos = rem & 3;
        int ksw = half * 32 + ((pos ^ ((r >> 1) & 3)) << 3);
        pB[i] = Bt + (size_t)(col0 + r) * K + ksw;
        ldB[i] = (unsigned)c * 16u;
    }
    char* lbaseA = (char*)&As[0][0];
    char* lbaseB = (char*)&Bs[0][0];

    auto stage = [&](int k0, int buf) {
        char* dA = lbaseA + (unsigned)buf * ABYTES;
        char* dB = lbaseB + (unsigned)buf * BBYTES;
        #pragma unroll
        for (int i = 0; i < A_LOADS; i++) gload16(pA[i] + k0, dA + ldA[i]);
        #pragma unroll
        for (int i = 0; i < B_LOADS; i++) gload16(pB[i] + k0, dB + ldB[i]);
    };

    // ---- hoisted LDS read offsets (bytes, loop-invariant) ----
    unsigned roA[KH][MFRAG], roB[KH][4];
    #pragma unroll
    for (int s = 0; s < KH; s++) {
        #pragma unroll
        for (int mt = 0; mt < MFRAG; mt++) {
            int r = wm + mt * 16 + l16;
            int pos = quad ^ ((r >> 1) & 3);
            roA[s][mt] = (unsigned)(s * MT * 32 + r * 32 + pos * 8) * 2u;
        }
        #pragma unroll
        for (int nt = 0; nt < 4; nt++) {
            int r = wn + nt * 16 + l16;
            int pos = quad ^ ((r >> 1) & 3);
            roB[s][nt] = (unsigned)(s * 4096 + r * 32 + pos * 8) * 2u;
        }
    }

    floatx4 acc[MFRAG][4] = {};

    auto compute = [&](int cur) {
        const char* bA = lbaseA + (unsigned)cur * ABYTES;
        const char* bB = lbaseB + (unsigned)cur * BBYTES;
        #pragma unroll
        for (int s = 0; s < KH; s++) {
            bf16x8 af[MFRAG], bfr[4];
            #pragma unroll
            for (int mt = 0; mt < MFRAG; mt++)
                af[mt] = *(const bf16x8*)(bA + roA[s][mt]);
            #pragma unroll
            for (int nt = 0; nt < 4; nt++)
                bfr[nt] = *(const bf16x8*)(bB + roB[s][nt]);
            #pragma unroll
            for (int mt = 0; mt < MFRAG; mt++)
                #pragma unroll
                for (int nt = 0; nt < 4; nt++)
                    acc[mt][nt] = __builtin_amdgcn_mfma_f32_16x16x32_bf16(
                        af[mt], bfr[nt], acc[mt][nt], 0, 0, 0);
        }
    };

    if constexpr (DEPTH == 3) {
        int T = K / (32 * KH);
        stage(0, 0);
        if (T > 1) stage(32 * KH, 1);
        for (int t = 0; t < T; t++) {
            if (t == T - 1) { asm volatile("s_waitcnt vmcnt(0)" ::: "memory"); }
            else            { asm volatile("s_waitcnt vmcnt(4)" ::: "memory"); }
            __builtin_amdgcn_s_barrier();
            if (t + 2 < T) stage((t + 2) * (32 * KH), (t + 2) % 3);
            compute(t % 3);
        }
    } else {
        stage(0, 0);
        int cur = 0;
        for (int k0 = 0; k0 < K; k0 += 32 * KH) {
            __syncthreads();
            if (k0 + 32 * KH < K) stage(k0 + 32 * KH, cur ^ 1);
            compute(cur);
            cur ^= 1;
        }
    }

    if (qkvmode) {
        #pragma unroll
        for (int mt = 0; mt < MFRAG; mt++) {
            int rbase = row0 + wm + mt * 16 + quad * 4;
            int bq_ = rbase >> 10, sb = rbase & 1023;
            #pragma unroll
            for (int nt = 0; nt < 4; nt++) {
                int col = col0 + wn + nt * 16 + l16;
                float bcol = bias[col];
                if (col < DD) {
                    int hh = col >> 6, e = col & 63;
                    bf16* base = qhg + (((size_t)bq_ * HH + hh) * SS + sb) * 64 + e;
                    #pragma unroll
                    for (int r = 0; r < 4; r++)
                        base[(size_t)r * 64] = __float2bfloat16(acc[mt][nt][r] + bcol);
                } else if (col < 2 * DD) {
                    int cc = col - DD, hh = cc >> 6, e = cc & 63;
                    bf16* base = khg + (((size_t)bq_ * HH + hh) * SS) * 64;
                    #pragma unroll
                    for (int r = 0; r < 4; r++) {
                        int s = sb + r;
                        int pos = (((e >> 3) ^ (s & 7)) << 3) | (e & 7);
                        base[(size_t)s * 64 + pos] = __float2bfloat16(acc[mt][nt][r] + bcol);
                    }
                } else {
                    int cc = col - 2 * DD, hh = cc >> 6, e = cc & 63;
                    int c_t = sb >> 3;
                    int sc = (c_t & ~7) | ((c_t & 7) ^ (e & 7));
                    size_t off = (((size_t)bq_ * HH + hh) * 64 + e) * SS + sc * 8 + (sb & 7);
                    ushort4 pk;
                    pk.x = f2bfbits(acc[mt][nt][0] + bcol);
                    pk.y = f2bfbits(acc[mt][nt][1] + bcol);
                    pk.z = f2bfbits(acc[mt][nt][2] + bcol);
                    pk.w = f2bfbits(acc[mt][nt][3] + bcol);
                    *(ushort4*)&vtg[off] = pk;
                }
            }
        }
        return;
    }

    #pragma unroll
    for (int mt = 0; mt < MFRAG; mt++) {
        int rbase = row0 + wm + mt * 16 + quad * 4;
        #pragma unroll
        for (int nt = 0; nt < 4; nt++) {
            int col = col0 + wn + nt * 16 + l16;
            float bcol = bias[col];
            #pragma unroll
            for (int r = 0; r < 4; r++) {
                int row = rbase + r;
                float v = acc[mt][nt][r] + bcol;
                if (act) v = gelu_fast(v);
                if (residf) v += residf[(size_t)row * N + col];
                if (residb) v += __bfloat162float(residb[(size_t)row * N + col]);
                if (out_bf16) ((bf16*)Cout)[(size_t)row * N + col] = __float2bfloat16(v);
                else          ((float*)Cout)[(size_t)row * N + col] = v;
            }
        }
    }
}

// ---------------- MFMA flash attention: S^T form, no-max softmax -------------------
__global__ __launch_bounds__(256) void attn_mfma(
    const bf16* __restrict__ qh, const bf16* __restrict__ kh,
    const bf16* __restrict__ vT, bf16* __restrict__ ao)
{
    __shared__ bf16 Ks[2][64 * 64];
    __shared__ bf16 Vs[2][64 * 64];
    __shared__ bf16 Ps[128 * 64];

    int tid = threadIdx.x;
    int wave = tid >> 6, lane = tid & 63;
    int l16 = lane & 15, quad = lane >> 4;
    int id = blockIdx.x;
    int bh = (id & 7) * 12 + ((id >> 3) >> 3);
    int b = bh / HH, h = bh % HH;
    int s0 = ((id >> 3) & 7) * 128;
    int wm = wave * 32;

    const bf16* qbase = qh + ((size_t)bh * SS) * HDD;
    const bf16* kbase = kh + ((size_t)bh * SS) * HDD;
    const bf16* vbase = vT + ((size_t)bh * HDD) * SS;

    auto stage = [&](int t0, int buf) {
        #pragma unroll
        for (int i = 0; i < 2; i++) {
            int c = tid + i * 256;
            gload16(kbase + (size_t)t0 * 64 + c * 8, &Ks[buf][c * 8]);
            gload16(vbase + (size_t)(c >> 3) * SS + t0 + (c & 7) * 8, &Vs[buf][c * 8]);
        }
    };

    bf16x8 qf[2][2];
    #pragma unroll
    for (int mt = 0; mt < 2; mt++)
        #pragma unroll
        for (int ks = 0; ks < 2; ks++)
            qf[mt][ks] = *(const bf16x8*)(qbase +
                (size_t)(s0 + wm + mt * 16 + l16) * HDD + ks * 32 + quad * 8);

    floatx4 oaccT[4][2] = {};
    float lsum[2] = {};

    stage(0, 0);
    int cur = 0;
    for (int t0 = 0; t0 < SS; t0 += 64) {
        __syncthreads();
        if (t0 + 64 < SS) stage(t0 + 64, cur ^ 1);

        floatx4 st[4][2] = {};
        #pragma unroll
        for (int tt = 0; tt < 4; tt++) {
            int t = tt * 16 + l16;
            #pragma unroll
            for (int ks = 0; ks < 2; ks++) {
                int pos = (quad + 4 * ks) ^ (t & 7);
                bf16x8 kf = *(const bf16x8*)(&Ks[cur][t * 64 + pos * 8]);
                #pragma unroll
                for (int mt = 0; mt < 2; mt++)
                    st[tt][mt] = __builtin_amdgcn_mfma_f32_16x16x32_bf16(
                        kf, qf[mt][ks], st[tt][mt], 0, 0, 0);
            }
        }

        #pragma unroll
        for (int tt = 0; tt < 4; tt++)
            #pragma unroll
            for (int mt = 0; mt < 2; mt++) {
                float p0 = __expf(st[tt][mt][0]);
                float p1 = __expf(st[tt][mt][1]);
                float p2 = __expf(st[tt][mt][2]);
                float p3 = __expf(st[tt][mt][3]);
                lsum[mt] += (p0 + p1) + (p2 + p3);
                int m = wm + mt * 16 + l16;
                int c = tt * 2 + (quad >> 1);
                ushort4 pk;
                pk.x = f2bfbits(p0); pk.y = f2bfbits(p1);
                pk.z = f2bfbits(p2); pk.w = f2bfbits(p3);
                *(ushort4*)&Ps[m * 64 + ((c ^ (m & 7)) << 3) + (quad & 1) * 4] = pk;
            }

        #pragma unroll
        for (int ks = 0; ks < 2; ks++) {
            bf16x8 pf[2];
            #pragma unroll
            for (int mt = 0; mt < 2; mt++) {
                int m = wm + mt * 16 + l16;
                pf[mt] = *(const bf16x8*)(&Ps[m * 64 + (((quad + 4 * ks) ^ (m & 7)) << 3)]);
            }
            #pragma unroll
            for (int et = 0; et < 4; et++) {
                int e = et * 16 + l16;
                int vpos = (quad + 4 * ks) ^ (e & 7);
                bf16x8 vf = *(const bf16x8*)(&Vs[cur][e * 64 + vpos * 8]);
                #pragma unroll
                for (int mt = 0; mt < 2; mt++)
                    oaccT[et][mt] = __builtin_amdgcn_mfma_f32_16x16x32_bf16(
                        vf, pf[mt], oaccT[et][mt], 0, 0, 0);
            }
        }
        cur ^= 1;
    }

    float linv[2];
    #pragma unroll
    for (int mt = 0; mt < 2; mt++) {
        float l = lsum[mt];
        l += __shfl_xor(l, 16, 64);
        l += __shfl_xor(l, 32, 64);
        linv[mt] = __builtin_amdgcn_rcpf(l);
    }
    #pragma unroll
    for (int et = 0; et < 4; et++)
        #pragma unroll
        for (int mt = 0; mt < 2; mt++) {
            int m = wm + mt * 16 + l16;
            int c = et * 2 + (quad >> 1);
            ushort4 pk;
            pk.x = f2bfbits(oaccT[et][mt][0] * linv[mt]);
            pk.y = f2bfbits(oaccT[et][mt][1] * linv[mt]);
            pk.z = f2bfbits(oaccT[et][mt][2] * linv[mt]);
            pk.w = f2bfbits(oaccT[et][mt][3] * linv[mt]);
            *(ushort4*)&Ps[m * 64 + ((c ^ (m & 7)) << 3) + (quad & 1) * 4] = pk;
        }
    int mrow = wm + (lane >> 1);
    bf16* op = ao + ((size_t)b * SS + s0 + mrow) * DD + h * HDD;
    #pragma unroll
    for (int i = 0; i < 4; i++) {
        int j = (lane & 1) * 4 + i;
        bf16x8 v = *(const bf16x8*)&Ps[mrow * 64 + ((j ^ (mrow & 7)) << 3)];
        *(bf16x8*)&op[j * 8] = v;
    }
}

// -----------------------------------------------------------------------------------
extern "C" void kernel_launch(void* const* d_in, const int* in_sizes, int n_in,
                              void* d_out, int out_size, void* d_ws, size_t ws_size,
                              hipStream_t stream)
{
    (void)in_sizes; (void)n_in; (void)out_size; (void)ws_size;
    const float* x    = (const float*)d_in[0];
    const float* ln1w = (const float*)d_in[1];
    const float* ln1b = (const float*)d_in[2];
    const float* Wq   = (const float*)d_in[3];
    const float* bq   = (const float*)d_in[4];
    const float* Wk   = (const float*)d_in[5];
    const float* bk   = (const float*)d_in[6];
    const float* Wv   = (const float*)d_in[7];
    const float* bv   = (const float*)d_in[8];
    const float* Wp   = (const float*)d_in[9];
    const float* bp   = (const float*)d_in[10];
    const float* ln2w = (const float*)d_in[11];
    const float* ln2b = (const float*)d_in[12];
    const float* W1   = (const float*)d_in[13];
    const float* b1   = (const float*)d_in[14];
    const float* W2   = (const float*)d_in[15];
    const float* b2   = (const float*)d_in[16];
    float* out = (float*)d_out;

    char* p = (char*)d_ws;
    auto alloc = [&](size_t bytes) { char* r = p; p += (bytes + 255) & ~255ull; return r; };
    bf16*  Wqkvt = (bf16*)alloc((size_t)QKVN * DD * 2);
    bf16*  Wpt   = (bf16*)alloc((size_t)DD * DD * 2);
    bf16*  W1t   = (bf16*)alloc((size_t)FFF * DD * 2);
    bf16*  W2t   = (bf16*)alloc((size_t)DD * FFF * 2);
    float* bqkv  = (float*)alloc((size_t)QKVN * 4);
    bf16*  yb    = (bf16*)alloc((size_t)NROW * DD * 2);
    bf16*  x1b   = (bf16*)alloc((size_t)NROW * DD * 2);        // residual stream 1, bf16
    char*  dynr  = alloc((size_t)NROW * DD * 2 + 3 * ((size_t)NROW * DD * 2));
    bf16*  aob   = (bf16*)dynr;                                // [row][768]
    bf16*  qhb   = (bf16*)(dynr + (size_t)NROW * DD * 2);      // [bh][s][64]
    bf16*  khb   = qhb + (size_t)NROW * DD;                    // swizzled
    bf16*  vtb   = khb + (size_t)NROW * DD;                    // [bh][e][1024] swizzled
    bf16*  hb    = (bf16*)dynr;   // FF intermediate (50MB) reuses aob+qkv region

    prep_kernel<<<6915, 256, 0, stream>>>(Wq, Wk, Wv, Wp, W1, W2, bq, bk, bv,
                                          Wqkvt, Wpt, W1t, W2t, bqkv);

    ln_kernel<float><<<NROW/4, 256, 0, stream>>>(x, ln1w, ln1b, yb);

    // fused QKV GEMM, head-separating scatter (MT=128 DEPTH=3, col-major slots)
    mfma_gemm<128,1,3><<<1152, 256, 0, stream>>>(
        yb, Wqkvt, bqkv, nullptr, nullptr, nullptr, NROW, QKVN, DD, 0, 0, 18, 8,
        1, qhb, khb, vtb);

    attn_mfma<<<dim3(BB*HH*(SS/128)), 256, 0, stream>>>(qhb, khb, vtb, aob);

    // projection + GELU + residual(x fp32) -> x1 bf16  (MT=64 DEPTH=2)
    mfma_gemm<64,2,2><<<768, 256, 0, stream>>>(
        aob, Wpt, bp, x, nullptr, x1b, NROW, DD, DD, 1, 1, 6, 16,
        0, nullptr, nullptr, nullptr);

    ln_kernel<bf16><<<NROW/4, 256, 0, stream>>>(x1b, ln2w, ln2b, yb);

    // FF1 + GELU -> hb bf16  (MT=64/KH=2/DEPTH=2, col-major slots)
    mfma_gemm<64,2,2><<<3072, 256, 0, stream>>>(
        yb, W1t, b1, nullptr, nullptr, hb, NROW, FFF, DD, 1, 1, 24, 16,
        0, nullptr, nullptr, nullptr);

    // FF2 + GELU + residual(x1 bf16) -> out fp32  (MT=64 DEPTH=2, col-major slots)
    mfma_gemm<64,2,2><<<768, 256, 0, stream>>>(
        hb, W2t, b2, nullptr, x1b, out, NROW, DD, FFF, 1, 0, 6, 16,
        0, nullptr, nullptr, nullptr);
}